// Round 3
// baseline (2051.135 us; speedup 1.0000x reference)
//
#include <hip/hip_runtime.h>

// ---------------- problem constants ----------------
#define NDIST   45
#define NANG    7
#define NTOW    52          // 45 dist + 7 angle towers
#define NSLICE  64          // workgroups per tower -> grid 3328 = 13 exact rounds on 256 CUs
#define BF      64          // frames per frame-block
#define NIT     64          // frame-blocks per workgroup (262144/NSLICE/BF)
#define HSTRIDE 132         // f16 per LDS row: 264B -> row stride 66 words == 2 mod 32 (conflict-min)
#define BUFSZ   (BF * HSTRIDE)

typedef _Float16 f16;
typedef _Float16 f16x2 __attribute__((ext_vector_type(2)));
typedef _Float16 f16x4 __attribute__((ext_vector_type(4)));
typedef _Float16 f16x8 __attribute__((ext_vector_type(8)));
typedef float    f32x4 __attribute__((ext_vector_type(4)));

__device__ __forceinline__ f16x2 splat2(float v) { f16x2 r; r[0] = (f16)v; r[1] = (f16)v; return r; }
__device__ __forceinline__ f16x2 mk2(f16 a, f16 b) { f16x2 r; r[0] = a; r[1] = b; return r; }
__device__ __forceinline__ f16x2 pkrtz(float a, float b) {
  return __builtin_bit_cast(f16x2, __builtin_amdgcn_cvt_pkrtz(a, b));
}

// tanh(x) ~= xc * P(xc^2), xc = clamp(x, +-2.6); deg-4 Horner. Error budget huge (thr 2.6e10).
__device__ __forceinline__ f16x2 tanh_pk(f16x2 x) {
  x = __builtin_elementwise_max(x, splat2(-2.6f));
  x = __builtin_elementwise_min(x, splat2( 2.6f));
  f16x2 u = x * x;
  f16x2 p = u * splat2(0.00053778f) + splat2(-0.01005094f);
  p = u * p + splat2(0.07382459f);
  p = u * p + splat2(-0.29688618f);
  p = u * p + splat2(0.99552470f);
  return x * p;
}

// MFMA 16x16x32 f16 layout (verified rounds 1-2, absmax 0):
//   A-frag: lane l supplies A[m = l&15][k = 32*ks + 8*(l>>4) + j], j=0..7
//   B-frag: lane l supplies B[k = 32*ks + 8*(l>>4) + j][n = l&15]
//   D:      lane l, reg r holds D[m = 4*(l>>4) + r][n = l&15]
//
// Layer-split waves: waves 0-3 (role 0) hold 64 rows of W1^T (h = wid&1 half,
// sg = (wid>>1)&1 strip-group) and run gemm1; waves 4-7 (role 1) same for
// layer 2 + output dot. areg = 64 VGPR/wave -> 4 waves/SIMD possible.
// Per iter (one barrier): gemm1(it-1): H0->H1 ; gemm2(it-2): H1->accY ;
// layer0(it): x->H0 split over all 8 waves. H0/H1 double-buffered by parity.

__global__ __launch_bounds__(512, 4)
void towers_kernel(const float* __restrict__ F_dist, const float* __restrict__ F_cos,
                   const float* __restrict__ F_sin,
                   const float* __restrict__ Zd,  const float* __restrict__ Zc,
                   const float* __restrict__ Zs,  const float* __restrict__ BC,
                   const float* __restrict__ W1d, const float* __restrict__ b1d,
                   const float* __restrict__ Whd, const float* __restrict__ bhd,
                   const float* __restrict__ Wod, const float* __restrict__ bod,
                   const float* __restrict__ W1a, const float* __restrict__ b1a,
                   const float* __restrict__ Wha, const float* __restrict__ bha,
                   const float* __restrict__ Woa, const float* __restrict__ boa,
                   float* __restrict__ out)
{
  __shared__ __align__(16) f16 buf[4 * BUFSZ];     // H0 = buf[0,1], H1 = buf[2,3]; also W-stage scratch
  __shared__ __align__(16) f16 sW1x[128], sW1y[128], sB1[128];
  __shared__ __align__(16) f16 sBg1[128], sBg2[128], sWo[128];
  __shared__ float sScal[8];
  __shared__ float sRed[8];

  const int tid  = threadIdx.x;
  const int wid  = tid >> 6;
  const int lane = tid & 63;
  const int fl   = lane & 15;
  const int g    = lane >> 4;
  const int role = wid >> 2;       // 0: gemm1 waves, 1: gemm2 waves
  const int h    = wid & 1;        // 64-row half of W^T
  const int sg   = (wid >> 1) & 1; // strip group: strips {2sg, 2sg+1}
  const int T     = blockIdx.x / NSLICE;
  const int slice = blockIdx.x - T * NSLICE;
  const bool isDist = (T < NDIST);
  const int Ai = T - NDIST;

  // ---- stage small per-tower params ----
  if (tid < 128) {
    const int n = tid;
    float w1x, w1y, b1v, bg1, bg2, wov;
    if (isDist) {
      w1x = W1d[T*128+n]; w1y = 0.f; b1v = b1d[T*128+n];
      bg1 = bhd[(0*NDIST+T)*128+n]; bg2 = bhd[(1*NDIST+T)*128+n]; wov = Wod[T*128+n];
    } else {
      w1x = W1a[(Ai*2+0)*128+n]; w1y = W1a[(Ai*2+1)*128+n]; b1v = b1a[Ai*128+n];
      bg1 = bha[(0*NANG+Ai)*128+n]; bg2 = bha[(1*NANG+Ai)*128+n]; wov = Woa[Ai*128+n];
    }
    sW1x[n] = (f16)w1x; sW1y[n] = (f16)w1y; sB1[n] = (f16)b1v;
    sBg1[n] = (f16)bg1; sBg2[n] = (f16)bg2; sWo[n] = (f16)wov;
  }
  if (tid == 0) {
    if (isDist) { sScal[0]=Zd[T]; sScal[1]=1.f/Zd[NDIST+T]; sScal[2]=0.f; sScal[3]=0.f; sScal[4]=bod[T]; }
    else { sScal[0]=Zc[0]; sScal[1]=1.f/Zc[NANG]; sScal[2]=Zs[0]; sScal[3]=1.f/Zs[NANG]; sScal[4]=boa[Ai]; }
  }

  // ---- stage Wt = W^T (f16) into buf[0..1] (128x132); role-l waves grab their areg ----
  const float* __restrict__ WhB = isDist ? (Whd + (size_t)T*16384) : (Wha + (size_t)Ai*16384);
  const size_t Wls = isDist ? (size_t)NDIST*16384 : (size_t)NANG*16384;
  f16x8 areg[4][4];

  #pragma unroll 1
  for (int l = 0; l < 2; ++l) {
    const float* __restrict__ src = WhB + (size_t)l * Wls;
    const int m = tid & 127;
    #pragma unroll 4
    for (int p = 0; p < 16; ++p) {
      const int n = 2*((tid >> 7) + 4*p);
      f16x2 v; v[0] = (f16)src[(size_t)n*128 + m]; v[1] = (f16)src[(size_t)(n+1)*128 + m];
      *(f16x2*)&buf[m*HSTRIDE + n] = v;            // Wt[m][n] = Wh[n][m]
    }
    __syncthreads();
    if (role == l) {
      #pragma unroll
      for (int mt = 0; mt < 4; ++mt)
        #pragma unroll
        for (int ks = 0; ks < 4; ++ks)
          areg[mt][ks] = *(const f16x8*)&buf[(64*h + 16*mt + fl)*HSTRIDE + 32*ks + 8*g];
    }
    __syncthreads();
  }

  const float zm0 = sScal[0], zsi0 = sScal[1], zm1 = sScal[2], zsi1 = sScal[3];
  const int fq = tid >> 4;                 // 0..31
  const int n0 = 8 * (tid & 15);
  const int rbo = 64*h + 4*g;              // bias/wo row base (+16*mt)

  // bond/repel fold (each frame's x loaded by 16 threads -> scale 1/16)
  float bK = 0.f, bEq = 0.f;
  if (isDist && T < 9) { bK = 0.03125f * BC[T]; bEq = BC[16 + T]; }   // 0.5/16 * k
  const bool doRep = isDist && (T >= 17);

  float accY = 0.f;
  const size_t fbase = (size_t)slice * (BF * NIT);

  #pragma unroll 1
  for (int it = 0; it < NIT + 2; ++it) {
    // ---- issue x loads for fblock it (consumed at end of iter by layer0) ----
    float xra, xrb, yra, yrb;
    if (it < NIT) {
      const size_t f0 = fbase + (size_t)it * BF + fq;
      if (isDist) { xra = F_dist[f0*NDIST + T]; xrb = F_dist[(f0+32)*NDIST + T]; }
      else { xra = F_cos[f0*NANG]; xrb = F_cos[(f0+32)*NANG];
             yra = F_sin[f0*NANG]; yrb = F_sin[(f0+32)*NANG]; }
    }

    if (role == 0) {
      // ---- gemm1(it-1): H0[(it-1)&1] -> tanh -> H1[(it-1)&1] ----
      if (it >= 1 && it <= NIT) {
        const f16* __restrict__ Hr = buf + ((it-1) & 1) * BUFSZ;
        f16*       __restrict__ Hw = buf + (2 + ((it-1) & 1)) * BUFSZ;
        #pragma unroll 1
        for (int si = 0; si < 2; ++si) {
          const int row = 16*(2*sg + si) + fl;
          const f16* __restrict__ hp = Hr + row*HSTRIDE + 8*g;
          f32x4 a0 = {0,0,0,0}, a1 = {0,0,0,0}, a2 = {0,0,0,0}, a3 = {0,0,0,0};
          __builtin_amdgcn_s_setprio(1);
          #pragma unroll
          for (int ks = 0; ks < 4; ++ks) {
            const f16x8 b = *(const f16x8*)(hp + 32*ks);
            a0 = __builtin_amdgcn_mfma_f32_16x16x32_f16(areg[0][ks], b, a0, 0, 0, 0);
            a1 = __builtin_amdgcn_mfma_f32_16x16x32_f16(areg[1][ks], b, a1, 0, 0, 0);
            a2 = __builtin_amdgcn_mfma_f32_16x16x32_f16(areg[2][ks], b, a2, 0, 0, 0);
            a3 = __builtin_amdgcn_mfma_f32_16x16x32_f16(areg[3][ks], b, a3, 0, 0, 0);
          }
          __builtin_amdgcn_s_setprio(0);
          f16* __restrict__ wp = Hw + row*HSTRIDE + rbo;
          f32x4 acc[4] = {a0, a1, a2, a3};
          #pragma unroll
          for (int mt = 0; mt < 4; ++mt) {
            const f16x4 bw = *(const f16x4*)&sBg1[rbo + 16*mt];
            f16x2 lo = pkrtz(acc[mt][0], acc[mt][1]) + mk2(bw[0], bw[1]);
            f16x2 hi = pkrtz(acc[mt][2], acc[mt][3]) + mk2(bw[2], bw[3]);
            lo = tanh_pk(lo); hi = tanh_pk(hi);
            f16x4 o; o[0] = lo[0]; o[1] = lo[1]; o[2] = hi[0]; o[3] = hi[1];
            *(f16x4*)(wp + 16*mt) = o;             // H1[frame][m_out]
          }
        }
      }
    } else {
      // ---- gemm2(it-2): H1[(it-2)&1] -> tanh -> dot(wo) -> accY ----
      if (it >= 2) {
        const f16* __restrict__ Hr = buf + (2 + (it & 1)) * BUFSZ;
        #pragma unroll 1
        for (int si = 0; si < 2; ++si) {
          const int row = 16*(2*sg + si) + fl;
          const f16* __restrict__ hp = Hr + row*HSTRIDE + 8*g;
          f32x4 a0 = {0,0,0,0}, a1 = {0,0,0,0}, a2 = {0,0,0,0}, a3 = {0,0,0,0};
          __builtin_amdgcn_s_setprio(1);
          #pragma unroll
          for (int ks = 0; ks < 4; ++ks) {
            const f16x8 b = *(const f16x8*)(hp + 32*ks);
            a0 = __builtin_amdgcn_mfma_f32_16x16x32_f16(areg[0][ks], b, a0, 0, 0, 0);
            a1 = __builtin_amdgcn_mfma_f32_16x16x32_f16(areg[1][ks], b, a1, 0, 0, 0);
            a2 = __builtin_amdgcn_mfma_f32_16x16x32_f16(areg[2][ks], b, a2, 0, 0, 0);
            a3 = __builtin_amdgcn_mfma_f32_16x16x32_f16(areg[3][ks], b, a3, 0, 0, 0);
          }
          __builtin_amdgcn_s_setprio(0);
          f32x4 acc[4] = {a0, a1, a2, a3};
          f16x2 y2 = splat2(0.f);
          #pragma unroll
          for (int mt = 0; mt < 4; ++mt) {
            const f16x4 bw  = *(const f16x4*)&sBg2[rbo + 16*mt];
            const f16x4 wo4 = *(const f16x4*)&sWo [rbo + 16*mt];
            f16x2 lo = pkrtz(acc[mt][0], acc[mt][1]) + mk2(bw[0], bw[1]);
            f16x2 hi = pkrtz(acc[mt][2], acc[mt][3]) + mk2(bw[2], bw[3]);
            lo = tanh_pk(lo); hi = tanh_pk(hi);
            y2 = y2 + lo * mk2(wo4[0], wo4[1]);
            y2 = y2 + hi * mk2(wo4[2], wo4[3]);
          }
          accY += (float)y2[0] + (float)y2[1];
        }
      }
    }

    // ---- layer0(it): x -> H0[it&1], split over all 8 waves; + folded bond/repel ----
    if (it < NIT) {
      f16* __restrict__ Hw = buf + (it & 1) * BUFSZ;
      const f16x8 w8  = *(const f16x8*)&sW1x[n0];   // per-iter LDS reads (barrier blocks hoist)
      const f16x8 b8  = *(const f16x8*)&sB1[n0];
      f16x8 w8y;
      if (!isDist) w8y = *(const f16x8*)&sW1y[n0];
      #pragma unroll
      for (int p = 0; p < 2; ++p) {
        const float xraw = p ? xrb : xra;
        if (bK != 0.f) { const float t = xraw - bEq; accY += bK * t * t; }
        if (doRep) {
          const float v2 = xraw * xraw;
          const float v6 = v2 * v2 * v2;
          accY += 1730.0400390625f * __builtin_amdgcn_rcpf(v6);   // 5.5^6/16 / d^6
        }
        const float xs = (xraw - zm0) * zsi0;
        const f16x2 xn = pkrtz(xs, xs);
        f16x2 yn;
        if (!isDist) { const float ys = ((p ? yrb : yra) - zm1) * zsi1; yn = pkrtz(ys, ys); }
        f16x8 h8;
        #pragma unroll
        for (int q = 0; q < 4; ++q) {
          f16x2 a = mk2(w8[2*q], w8[2*q+1]) * xn + mk2(b8[2*q], b8[2*q+1]);
          if (!isDist) a = a + mk2(w8y[2*q], w8y[2*q+1]) * yn;
          const f16x2 t = tanh_pk(a);
          h8[2*q] = t[0]; h8[2*q+1] = t[1];
        }
        *(f16x8*)&Hw[(fq + 32*p)*HSTRIDE + n0] = h8;
      }
    }
    __syncthreads();
  }

  // ---- single reduction at the end ----
  #pragma unroll
  for (int off = 1; off < 64; off <<= 1) accY += __shfl_xor(accY, off, 64);
  if (lane == 0) sRed[wid] = accY;
  __syncthreads();
  if (tid == 0) {
    float tot = sRed[0]+sRed[1]+sRed[2]+sRed[3]+sRed[4]+sRed[5]+sRed[6]+sRed[7];
    tot += sScal[4] * (float)(BF * NIT);   // + bo per frame
    atomicAdd(out, tot);
  }
}

// ---------------- angle-only bond (F_dist terms folded into towers_kernel) ----------------
__global__ __launch_bounds__(256)
void angle_bond_kernel(const float* __restrict__ Fa, const float* __restrict__ BC,
                       float* __restrict__ out)
{
  __shared__ float sa[256 * NANG];
  __shared__ float sred[4];
  const int tid = threadIdx.x;
  const size_t b0 = (size_t)blockIdx.x * 256;
  for (int k = tid; k < 256 * NANG; k += 256) sa[k] = Fa[b0 * NANG + k];
  __syncthreads();
  const float* a = &sa[tid * NANG];
  float bond = 0.f;
  #pragma unroll
  for (int j = 0; j < 7; ++j) { float t = a[j] - BC[16 + 9 + j]; bond += BC[9 + j] * t * t; }
  float u = 0.5f * bond;
  #pragma unroll
  for (int off = 32; off >= 1; off >>= 1) u += __shfl_xor(u, off, 64);
  if ((tid & 63) == 0) sred[tid >> 6] = u;
  __syncthreads();
  if (tid == 0) atomicAdd(out, sred[0] + sred[1] + sred[2] + sred[3]);
}

extern "C" void kernel_launch(void* const* d_in, const int* in_sizes, int n_in,
                              void* d_out, int out_size, void* d_ws, size_t ws_size,
                              hipStream_t stream)
{
  (void)in_sizes; (void)n_in; (void)d_ws; (void)ws_size; (void)out_size;
  const float* F_dist  = (const float*)d_in[0];
  const float* F_cos   = (const float*)d_in[1];
  const float* F_sin   = (const float*)d_in[2];
  const float* F_angle = (const float*)d_in[3];
  const float* Zd      = (const float*)d_in[4];
  const float* Zc      = (const float*)d_in[5];
  const float* Zs      = (const float*)d_in[6];
  const float* BC      = (const float*)d_in[7];
  const float* W1d     = (const float*)d_in[8];
  const float* b1d     = (const float*)d_in[9];
  const float* Whd     = (const float*)d_in[10];
  const float* bhd     = (const float*)d_in[11];
  const float* Wod     = (const float*)d_in[12];
  const float* bod     = (const float*)d_in[13];
  const float* W1a     = (const float*)d_in[14];
  const float* b1a     = (const float*)d_in[15];
  const float* Wha     = (const float*)d_in[16];
  const float* bha     = (const float*)d_in[17];
  const float* Woa     = (const float*)d_in[18];
  const float* boa     = (const float*)d_in[19];
  float* out = (float*)d_out;

  hipMemsetAsync(d_out, 0, sizeof(float), stream);
  angle_bond_kernel<<<dim3(262144 / 256), dim3(256), 0, stream>>>(F_angle, BC, out);
  towers_kernel<<<dim3(NTOW * NSLICE), dim3(512), 0, stream>>>(
      F_dist, F_cos, F_sin, Zd, Zc, Zs, BC,
      W1d, b1d, Whd, bhd, Wod, bod,
      W1a, b1a, Wha, bha, Woa, boa, out);
}